// Round 15
// baseline (173.751 us; speedup 1.0000x reference)
//
#include <hip/hip_runtime.h>
#include <math.h>

#define B_ 8
#define T_ 1024
#define F_ 256
#define H_ 256
#define BT_ (B_*T_)          // 8192
constexpr float EPS = 1e-5f;
// 1/sqrt(256) * log2(e), folded into qbuf: softmax uses raw v_exp_f32 (exp2).
constexpr float SCALE_L2E = 0.09016844005555963f;

typedef unsigned int u32;
typedef unsigned short u16;
typedef __attribute__((ext_vector_type(8))) short bf16x8;    // 8 bf16 = 4 VGPRs
typedef __attribute__((ext_vector_type(4))) float f32x4;
typedef __attribute__((ext_vector_type(16))) float f32x16;

// ---------- bf16 helpers ----------
__device__ __forceinline__ float bf1(u16 p) { return __uint_as_float(((u32)p) << 16); }
__device__ __forceinline__ u16 f2bf(float f) {
  u32 u = __float_as_uint(f);
  u32 r = u + 0x7FFFu + ((u >> 16) & 1u);   // RNE
  return (u16)(r >> 16);
}

__device__ __forceinline__ f32x4 mfma16(bf16x8 a, bf16x8 b, f32x4 c) {
  return __builtin_amdgcn_mfma_f32_16x16x32_bf16(a, b, c, 0, 0, 0);
}
__device__ __forceinline__ f32x16 mfma32(bf16x8 a, bf16x8 b, f32x16 c) {
  return __builtin_amdgcn_mfma_f32_32x32x16_bf16(a, b, c, 0, 0, 0);
}

// async global->LDS, 16B per lane; dest = wave-uniform base + lane*16
__device__ __forceinline__ void gload_lds16(const u16* g, u16* l) {
  __builtin_amdgcn_global_load_lds(
      (const __attribute__((address_space(1))) u32*)(uintptr_t)g,
      (__attribute__((address_space(3))) u32*)(u32)(uintptr_t)l,
      16, 0, 0);
}

// ---------- block-wide reduction of 4 values over 256 threads ----------
__device__ __forceinline__ void block_reduce4(float& a, float& b, float& c, float& d) {
  #pragma unroll
  for (int off = 32; off > 0; off >>= 1) {
    a += __shfl_down(a, off, 64);
    b += __shfl_down(b, off, 64);
    c += __shfl_down(c, off, 64);
    d += __shfl_down(d, off, 64);
  }
  __shared__ float red[4][4];
  int wid = threadIdx.x >> 6;
  int lane = threadIdx.x & 63;
  if (lane == 0) { red[0][wid] = a; red[1][wid] = b; red[2][wid] = c; red[3][wid] = d; }
  __syncthreads();
  a = red[0][0] + red[0][1] + red[0][2] + red[0][3];
  b = red[1][0] + red[1][1] + red[1][2] + red[1][3];
  c = red[2][0] + red[2][1] + red[2][2] + red[2][3];
  d = red[3][0] + red[3][1] + red[3][2] + red[3][3];
}

// ---------- K1 (fused): blocks 0..8191 = LayerNorm-1; 8192..8575 = weight prep.
__global__ __launch_bounds__(256) void prep_kernel(
    const float* __restrict__ x, const float* __restrict__ w, const float* __restrict__ bi,
    u16* __restrict__ xnr, u16* __restrict__ xni,
    const float* __restrict__ Wq, const float* __restrict__ Wk, const float* __restrict__ Wv,
    u16* __restrict__ wT) {
  const int tid = threadIdx.x;
  if (blockIdx.x < BT_) {
    // ---- ln1 body: LayerNorm over F per (b,t,plane); emit bf16 real/imag
    const int row = blockIdx.x;
    const int f = tid;
    float2 xv = reinterpret_cast<const float2*>(x)[row * F_ + f];
    float sr = xv.x, si = xv.y, sr2 = xv.x * xv.x, si2 = xv.y * xv.y;
    block_reduce4(sr, si, sr2, si2);
    const float inv = 1.0f / F_;
    float mr = sr * inv, mi = si * inv;
    float vr = sr2 * inv - mr * mr, vi = si2 * inv - mi * mi;
    float rr = rsqrtf(vr + EPS), ri = rsqrtf(vi + EPS);
    float ww = w[f], bb = bi[f];
    xnr[row * F_ + f] = f2bf((xv.x - mr) * rr * ww + bb);
    xni[row * F_ + f] = f2bf((xv.y - mi) * ri * ww + bb);
  } else {
    // ---- wprep body: transpose+convert W[z][f][h] (f32) -> wT[z][h][f] (bf16)
    const int wid = blockIdx.x - BT_;   // 0..383
    const int z = wid >> 4;             // 0..23
    const int r4 = wid & 15;
    const int ft = (r4 & 3) * 64;
    const int ht = (r4 >> 2) * 64;
    const int m = z >> 3, n = z & 7;
    const float* W = (m == 0 ? Wq : (m == 1 ? Wk : Wv)) + (size_t)n * F_ * H_;
    __shared__ __align__(16) u16 Ts[64][72];

    #pragma unroll
    for (int i = 0; i < 4; i++) {
      int id = tid + i * 256;
      int r = id >> 4, c4 = (id & 15) * 4;
      float4 p = *reinterpret_cast<const float4*>(&W[(size_t)(ft + r) * H_ + ht + c4]);
      Ts[r][c4 + 0] = f2bf(p.x); Ts[r][c4 + 1] = f2bf(p.y);
      Ts[r][c4 + 2] = f2bf(p.z); Ts[r][c4 + 3] = f2bf(p.w);
    }
    __syncthreads();
    u16* op = wT + (size_t)z * F_ * H_ + (size_t)ht * F_ + ft;
    #pragma unroll
    for (int i = 0; i < 2; i++) {
      int id = tid + i * 256;
      int hl = id & 63, g = id >> 6;
      u16 tmp[8];
      #pragma unroll
      for (int j = 0; j < 8; j++) tmp[j] = Ts[g * 8 + j][hl];
      *reinterpret_cast<uint4*>(op + (size_t)hl * F_ + g * 8) =
          *reinterpret_cast<const uint4*>(tmp);
    }
  }
}

// ---------- K2b: QKV projections — bf16 MFMA GEMM, 128x256 tile (full H) ----------
// R23 pipeline: counted-vmcnt double-buffer (attn-R14-proven template).
__global__ __launch_bounds__(256, 2) void qkv_kernel(
    const u16* __restrict__ xnr, const u16* __restrict__ xni, const u16* __restrict__ wT,
    const float* __restrict__ bq, const float* __restrict__ bk, const float* __restrict__ bv,
    u16* __restrict__ qo, u16* __restrict__ ko, u16* __restrict__ vTo) {
  const int z = blockIdx.y;
  const int m = z >> 3, n = z & 7;
  int sel; const float* bias; u16* out;
  if (m == 0)      { sel = (n >> 1) & 1;  bias = bq; out = qo + (size_t)n * BT_ * H_; }
  else if (m == 1) { sel = n & 1;         bias = bk; out = ko + (size_t)n * BT_ * H_; }
  else             { sel = __popc(n) & 1; bias = bv; out = nullptr; }
  const float osc = (m == 0) ? SCALE_L2E : 1.0f;   // q pre-scaled by 1/16*log2(e)
  const u16* A = sel ? xni : xnr;
  const u16* wp = wT + (size_t)z * F_ * H_;
  bias += n * H_;
  const int rowbase = blockIdx.x * 128;

  __shared__ __align__(16) u16 As[2][128 * 32];   // 16 KB, dbuf of BK=32 tiles
  __shared__ __align__(16) u16 Bs[2][256 * 32];   // 32 KB, dbuf of BK=32 tiles
  __shared__ __align__(16) u16 Epi[4][1536];      // q/k: [16][72]; v: [64][24]

  const int tid = threadIdx.x;
  const int wv = tid >> 6, lane = tid & 63;
  const int quad = lane >> 4, l16 = lane & 15;
  const int wrow = wv >> 1, wcol = wv & 1;        // wave: 64 rows x 128 cols

  f32x4 acc[4][8];
  #pragma unroll
  for (int i = 0; i < 4; i++)
    #pragma unroll
    for (int j = 0; j < 8; j++) acc[i][j] = (f32x4){0.f, 0.f, 0.f, 0.f};

  const int ar = tid >> 2;            // staging: row tid>>2, k-chunk (tid&3)*8
  const int ak = (tid & 3) * 8;

  // stage K-tile t (cols t*32..t*32+31) into buffer buf: 6 DMA instr-groups.
  auto stage = [&](int t, int buf) {
    const int kb = t * 32;
    gload_lds16(A + (size_t)(rowbase + ar) * F_ + kb + ak, &As[buf][tid * 8]);
    gload_lds16(A + (size_t)(rowbase + 64 + ar) * F_ + kb + ak,
                &As[buf][2048 + tid * 8]);
    #pragma unroll
    for (int c = 0; c < 4; c++)
      gload_lds16(wp + (size_t)(c * 64 + ar) * F_ + kb + ak,
                  &Bs[buf][c * 2048 + tid * 8]);
  };

  stage(0, 0);
  stage(1, 1);
  asm volatile("s_waitcnt vmcnt(6)" ::: "memory");   // tile 0 landed
  __builtin_amdgcn_s_barrier();
  __builtin_amdgcn_sched_barrier(0);

  #pragma unroll 1
  for (int t = 0; t < 8; t++) {
    const int c = t & 1;

    // ---- compute tile t from As[c]/Bs[c]: 12 ds_read_b128 + 32 mfma16
    bf16x8 a[4], b[8];
    #pragma unroll
    for (int mi = 0; mi < 4; mi++)
      a[mi] = *reinterpret_cast<const bf16x8*>(
          &As[c][(wrow * 64 + mi * 16 + l16) * 32 + quad * 8]);
    #pragma unroll
    for (int nj = 0; nj < 8; nj++)
      b[nj] = *reinterpret_cast<const bf16x8*>(
          &Bs[c][(wcol * 128 + nj * 16 + l16) * 32 + quad * 8]);
    __builtin_amdgcn_s_setprio(1);
    #pragma unroll
    for (int mi = 0; mi < 4; mi++)
      #pragma unroll
      for (int nj = 0; nj < 8; nj++)
        acc[mi][nj] = mfma16(a[mi], b[nj], acc[mi][nj]);
    __builtin_amdgcn_s_setprio(0);

    // ---- B1: all waves' reads of buf c retired -> c may be overwritten
    asm volatile("s_waitcnt lgkmcnt(0)" ::: "memory");
    __builtin_amdgcn_s_barrier();
    __builtin_amdgcn_sched_barrier(0);

    if (t < 6) stage(t + 2, c);

    // ---- B2: tile t+1 resident for all waves (counted vmcnt, no drain)
    if (t < 6) {
      asm volatile("s_waitcnt vmcnt(6)" ::: "memory");
    } else {
      asm volatile("s_waitcnt vmcnt(0)" ::: "memory");
    }
    __builtin_amdgcn_s_barrier();
    __builtin_amdgcn_sched_barrier(0);
  }

  float bias8[8];
  #pragma unroll
  for (int nj = 0; nj < 8; nj++)
    bias8[nj] = bias[wcol * 128 + nj * 16 + l16];

  if (m != 2) {   // q/k: row-major store, two 64-col passes
    #pragma unroll
    for (int pass = 0; pass < 2; pass++) {
      #pragma unroll
      for (int mi = 0; mi < 4; mi++) {
        #pragma unroll
        for (int nj4 = 0; nj4 < 4; nj4++) {
          int nj = pass * 4 + nj4;
          #pragma unroll
          for (int r = 0; r < 4; r++)
            Epi[wv][(quad * 4 + r) * 72 + nj4 * 16 + l16] =
                f2bf((acc[mi][nj][r] + bias8[nj]) * osc);
        }
        int row = rowbase + wrow * 64 + mi * 16 + l16;
        uint4 v0 = *reinterpret_cast<const uint4*>(&Epi[wv][l16 * 72 + quad * 16]);
        uint4 v1 = *reinterpret_cast<const uint4*>(&Epi[wv][l16 * 72 + quad * 16 + 8]);
        u16* op = out + (size_t)row * H_ + wcol * 128 + pass * 64 + quad * 16;
        *reinterpret_cast<uint4*>(op) = v0;
        *reinterpret_cast<uint4*>(op + 8) = v1;
      }
    }
  } else {        // v: transposed store into vT[n][h][bt], two 64-h passes
    #pragma unroll
    for (int pass = 0; pass < 2; pass++) {
      #pragma unroll
      for (int mi = 0; mi < 4; mi++) {
        #pragma unroll
        for (int nj4 = 0; nj4 < 4; nj4++) {
          int nj = pass * 4 + nj4;
          #pragma unroll
          for (int r = 0; r < 4; r++)
            Epi[wv][(nj4 * 16 + l16) * 24 + quad * 4 + r] =
                f2bf(acc[mi][nj][r] + bias8[nj]);
        }
        int hloc = lane;                  // 0..63
        uint4 w0 = *reinterpret_cast<const uint4*>(&Epi[wv][hloc * 24]);
        uint4 w1 = *reinterpret_cast<const uint4*>(&Epi[wv][hloc * 24 + 8]);
        u16* op = vTo + (size_t)n * H_ * BT_ +
                  (size_t)(wcol * 128 + pass * 64 + hloc) * BT_ +
                  rowbase + wrow * 64 + mi * 16;
        *reinterpret_cast<uint4*>(op) = w0;
        *reinterpret_cast<uint4*>(op + 8) = w1;
      }
    }
  }
}

// ---------- K3: MFMA flash attention ----------
// R24: R21/R22 loop body, grid 512 -> 256 blocks: each block runs TWO q-tiles
// (qt = 2*(fid>>6)+qq) sequentially. One dispatch round (1 block/CU resident),
// prologue amortized, tail halved. nb = fid&63 unchanged -> XCD locality
// preserved (all qt-blocks of an nb on XCD nb&7). Hazards: barrier at qq-loop
// top protects Ew scratch (in Ks[0]) vs next prologue DMA; prologue vmcnt(8)
// drains qq=0's epilogue stores (oldest) + tile-0 loads, leaving tile-1's 8.
__global__ __launch_bounds__(512, 2) void attn_kernel(
    const u16* __restrict__ q, const u16* __restrict__ k, const u16* __restrict__ vT,
    u16* __restrict__ obuf) {
  const int fid = blockIdx.x;        // 0..255
  const int nb = fid & 63;           // n*8 + b ; XCD = nb & 7
  const int n = nb >> 3, b = nb & 7;
  const int tid = threadIdx.x;
  const int wv = tid >> 6, lane = tid & 63;
  const int hi = lane >> 5, l32 = lane & 31;
  const int qh = wv >> 1;            // q 32-row group (0..3)
  const int kh = wv & 1;             // QK: key-half (32 keys)
  const int hh = wv & 1;             // PV: h-half (128 h)

  const size_t base = (size_t)nb * T_ * H_;
  const u16* qp = q + base;          // pre-scaled by SCALE_L2E
  const u16* kp = k + base;
  const u16* vtp = vT + ((size_t)n * H_ * B_ + b) * T_;

  __shared__ __align__(16) u16 Ks[2][64][256];   // 64 KB, 5-bit XOR swizzle
  __shared__ __align__(16) u16 Vs[2][64][256];   // 64 KB, packed-4h + 3-bit XOR
  __shared__ __align__(16) u16 Ps[4][32][72];    // 18,432 B (cols 64..67: l-sums)

  // K staging: 32 DMA instrs (4/wave), each fills 2 rows (512B each).
  auto stage_k = [&](int ktN, int buf) {
    #pragma unroll
    for (int i = 0; i < 4; i++) {
      int idx = wv * 4 + i;
      int row = 2 * idx + hi;
      const u16* src = kp + (size_t)(ktN * 64 + row) * H_ +
                       ((l32 ^ (row & 31)) * 8);
      gload_lds16(src, &Ks[buf][2 * idx][0]);
    }
  };
  // V staging: 32 DMA instrs (4/wave), each fills 2 physical rows.
  auto stage_v = [&](int ktN, int buf) {
    #pragma unroll
    for (int i = 0; i < 4; i++) {
      int idx = wv * 4 + i;
      int p = 2 * idx + hi;
      int u = l32 ^ (p & 7);
      const u16* src = vtp + (size_t)(p * 4 + (u >> 3)) * BT_ +
                       ktN * 64 + (u & 7) * 8;
      gload_lds16(src, &Vs[buf][2 * idx][0]);
    }
  };

  const int krow = kh * 32 + l32;

  #pragma unroll 1
  for (int qq = 0; qq < 2; qq++) {
    const int qt = (fid >> 6) * 2 + qq;   // 0..7 : 128 query rows
    const int qrow0 = qt * 128 + qh * 32;

    // Ew-scratch (in Ks[0]) from the previous qq must be fully read by all
    // waves before this prologue's DMA overwrites it.
    __syncthreads();

    bf16x8 qf[16];
    #pragma unroll
    for (int kc = 0; kc < 16; kc++)
      qf[kc] = *reinterpret_cast<const bf16x8*>(
          qp + (size_t)(qrow0 + l32) * H_ + kc * 16 + hi * 8);

    f32x16 o[4];
    #pragma unroll
    for (int ot = 0; ot < 4; ot++)
      #pragma unroll
      for (int r = 0; r < 16; r++) o[ot][r] = 0.f;
    float lper[16];
    #pragma unroll
    for (int r = 0; r < 16; r++) lper[r] = 0.f;

    // Prologue: stage tiles 0,1; vmcnt(8) leaves only tile-1's 8 loads
    // (epilogue stores + tile-0 loads are older -> drained).
    stage_k(0, 0); stage_v(0, 0);
    stage_k(1, 1); stage_v(1, 1);
    asm volatile("s_waitcnt vmcnt(8)" ::: "memory");
    __builtin_amdgcn_s_barrier();
    __builtin_amdgcn_sched_barrier(0);

    #pragma unroll 1
    for (int kt = 0; kt < 16; kt++) {
      const int c = kt & 1;

      // ---- QK phase: reads Ks[c]
      f32x16 sa, sb;
      #pragma unroll
      for (int r = 0; r < 16; r++) { sa[r] = 0.f; sb[r] = 0.f; }
      __builtin_amdgcn_s_setprio(1);
      #pragma unroll
      for (int kc = 0; kc < 16; kc += 2) {
        bf16x8 kfa = *reinterpret_cast<const bf16x8*>(
            &Ks[c][krow][(((kc * 2 + hi) ^ l32) * 8)]);
        bf16x8 kfb = *reinterpret_cast<const bf16x8*>(
            &Ks[c][krow][(((kc * 2 + 2 + hi) ^ l32) * 8)]);
        sa = mfma32(qf[kc], kfa, sa);
        sb = mfma32(qf[kc + 1], kfb, sb);
      }
      __builtin_amdgcn_s_setprio(0);

      #pragma unroll
      for (int r = 0; r < 16; r++) {
        float p = __builtin_amdgcn_exp2f(sa[r] + sb[r]);  // log2e pre-folded
        lper[r] += p;
        Ps[qh][(r & 3) + 8 * (r >> 2) + 4 * hi][kh * 32 + l32] = f2bf(p);
      }

      // ---- B1: Ps writes visible; Ks[c] readers (all waves) retired.
      asm volatile("s_waitcnt lgkmcnt(0)" ::: "memory");
      __builtin_amdgcn_s_barrier();
      __builtin_amdgcn_sched_barrier(0);

      if (kt < 14) stage_k(kt + 2, c);

      // ---- PV phase: reads Ps + Vs[c]
      bf16x8 pa[4];
      #pragma unroll
      for (int kc2 = 0; kc2 < 4; kc2++)
        pa[kc2] = *reinterpret_cast<const bf16x8*>(
            &Ps[qh][l32][kc2 * 16 + hi * 8]);
      __builtin_amdgcn_s_setprio(1);
      #pragma unroll
      for (int ot = 0; ot < 4; ot++) {
        const int p = hh * 32 + ot * 8 + (l32 >> 2);
        #pragma unroll
        for (int kc2 = 0; kc2 < 4; kc2++) {
          int s = ((l32 & 3) * 8 + kc2 * 2 + hi) ^ (l32 >> 2);
          bf16x8 vf = *reinterpret_cast<const bf16x8*>(&Vs[c][p][s * 8]);
          o[ot] = mfma32(pa[kc2], vf, o[ot]);
        }
      }
      __builtin_amdgcn_s_setprio(0);

      // ---- B2: own K/V(kt+1) landed; Vs[c]/Ps readers retired.
      if (kt < 14) {
        asm volatile("s_waitcnt vmcnt(4)" ::: "memory");
      } else {
        asm volatile("s_waitcnt vmcnt(0)" ::: "memory");
      }
      __builtin_amdgcn_s_barrier();
      __builtin_amdgcn_sched_barrier(0);

      if (kt < 14) stage_v(kt + 2, c);
    }

    #pragma unroll
    for (int r = 0; r < 16; r++) {
      #pragma unroll
      for (int off = 1; off < 32; off <<= 1)
        lper[r] += __shfl_xor(lper[r], off, 64);
    }
    if (l32 == 0) {
      #pragma unroll
      for (int r = 0; r < 16; r++) {
        int row = (r & 3) + 8 * (r >> 2) + 4 * hi;
        *reinterpret_cast<float*>(&Ps[qh][row][64 + 2 * kh]) = lper[r];
      }
    }
    __syncthreads();

    float invl[16];
    #pragma unroll
    for (int r = 0; r < 16; r++) {
      int row = (r & 3) + 8 * (r >> 2) + 4 * hi;
      float l0 = *reinterpret_cast<const float*>(&Ps[qh][row][64]);
      float l1 = *reinterpret_cast<const float*>(&Ps[qh][row][66]);
      invl[r] = 1.0f / (l0 + l1);
    }

    u16* Ew = reinterpret_cast<u16*>(&Ks[0][0][0]) + wv * 1280;  // 8x1280 u16
    const int grow = b * 1024 + qrow0 + l32;
    #pragma unroll
    for (int ot = 0; ot < 4; ot++) {
      #pragma unroll
      for (int r = 0; r < 16; r++) {
        int row = (r & 3) + 8 * (r >> 2) + 4 * hi;
        Ew[row * 40 + l32] = f2bf(o[ot][r] * invl[r]);
      }
      int ht = hh * 4 + ot;
      uint4 v0 = *reinterpret_cast<const uint4*>(&Ew[l32 * 40 + hi * 16]);
      uint4 v1 = *reinterpret_cast<const uint4*>(&Ew[l32 * 40 + hi * 16 + 8]);
      u16* op = obuf + (((size_t)n * 8 + ht) * BT_ + grow) * 32 + hi * 16;
      *reinterpret_cast<uint4*>(op) = v0;
      *reinterpret_cast<uint4*>(op + 8) = v1;
    }
  }
}

// ---------- K4: combine 8 branches (signed) + LayerNorm over H ----------
__global__ __launch_bounds__(256) void combine_ln2_kernel(
    const u16* __restrict__ obuf, const float* __restrict__ w,
    const float* __restrict__ bi, float* __restrict__ out) {
  const int row = blockIdx.x;
  const int h = threadIdx.x;
  float o[8];
  #pragma unroll
  for (int nn = 0; nn < 8; nn++)
    o[nn] = bf1(obuf[(((size_t)nn * 8 + (h >> 5)) * BT_ + row) * 32 + (h & 31)]);
  float re = o[0] - o[1] - o[2] - o[3];
  float im = o[4] + o[5] + o[6] - o[7];
  float sr = re, si = im, sr2 = re * re, si2 = im * im;
  block_reduce4(sr, si, sr2, si2);
  const float inv = 1.0f / H_;
  float mr = sr * inv, mi = si * inv;
  float vr = sr2 * inv - mr * mr, vi = si2 * inv - mi * mi;
  float rr = rsqrtf(vr + EPS), ri = rsqrtf(vi + EPS);
  float ww = w[h], bb = bi[h];
  float2 res;
  res.x = (re - mr) * rr * ww + bb;
  res.y = (im - mi) * ri * ww + bb;
  reinterpret_cast<float2*>(out)[(size_t)row * H_ + h] = res;
}

extern "C" void kernel_launch(void* const* d_in, const int* in_sizes, int n_in,
                              void* d_out, int out_size, void* d_ws, size_t ws_size,
                              hipStream_t stream) {
  const float* x    = (const float*)d_in[0];
  const float* Wq   = (const float*)d_in[1];
  const float* bq   = (const float*)d_in[2];
  const float* Wk   = (const float*)d_in[3];
  const float* bk   = (const float*)d_in[4];
  const float* Wv   = (const float*)d_in[5];
  const float* bv   = (const float*)d_in[6];
  const float* ln1w = (const float*)d_in[7];
  const float* ln1b = (const float*)d_in[8];
  const float* ln2w = (const float*)d_in[9];
  const float* ln2b = (const float*)d_in[10];

  // Workspace (128 MB), lifetime-aliased:
  //  [0,8)  xn  (dead after qkv)  |  [0,32)  obuf (written by attn, after qkv)
  //  [8,11) wT  (dead after qkv)
  //  [32,64) vT ; [64,96) q ; [96,128) k
  char* ws = (char*)d_ws;
  u16* xnr  = (u16*)(ws);
  u16* xni  = (u16*)(ws + (4ull  << 20));
  u16* wTb  = (u16*)(ws + (8ull  << 20));
  u16* obuf = (u16*)(ws);
  u16* vT   = (u16*)(ws + (32ull << 20));
  u16* qbuf = (u16*)(ws + (64ull << 20));
  u16* kbuf = (u16*)(ws + (96ull << 20));

  prep_kernel<<<BT_ + 384, 256, 0, stream>>>(x, ln1w, ln1b, xnr, xni,
                                             Wq, Wk, Wv, wTb);
  qkv_kernel<<<dim3(64, 24), 256, 0, stream>>>(xnr, xni, wTb, bq, bk, bv,
                                               qbuf, kbuf, vT);
  attn_kernel<<<dim3(256), 512, 0, stream>>>(qbuf, kbuf, vT, obuf);
  combine_ln2_kernel<<<BT_, 256, 0, stream>>>(obuf, ln2w, ln2b, (float*)d_out);
}

// Round 16
// 165.763 us; speedup vs baseline: 1.0482x; 1.0482x over previous
//
#include <hip/hip_runtime.h>
#include <math.h>

#define B_ 8
#define T_ 1024
#define F_ 256
#define H_ 256
#define BT_ (B_*T_)          // 8192
constexpr float EPS = 1e-5f;
// 1/sqrt(256) * log2(e), folded into qbuf: softmax uses raw v_exp_f32 (exp2).
constexpr float SCALE_L2E = 0.09016844005555963f;

typedef unsigned int u32;
typedef unsigned short u16;
typedef __attribute__((ext_vector_type(8))) short bf16x8;    // 8 bf16 = 4 VGPRs
typedef __attribute__((ext_vector_type(4))) float f32x4;
typedef __attribute__((ext_vector_type(16))) float f32x16;

// ---------- bf16 helpers ----------
__device__ __forceinline__ float bf1(u16 p) { return __uint_as_float(((u32)p) << 16); }
__device__ __forceinline__ u16 f2bf(float f) {
  u32 u = __float_as_uint(f);
  u32 r = u + 0x7FFFu + ((u >> 16) & 1u);   // RNE
  return (u16)(r >> 16);
}

__device__ __forceinline__ f32x4 mfma16(bf16x8 a, bf16x8 b, f32x4 c) {
  return __builtin_amdgcn_mfma_f32_16x16x32_bf16(a, b, c, 0, 0, 0);
}
__device__ __forceinline__ f32x16 mfma32(bf16x8 a, bf16x8 b, f32x16 c) {
  return __builtin_amdgcn_mfma_f32_32x32x16_bf16(a, b, c, 0, 0, 0);
}

// async global->LDS, 16B per lane; dest = wave-uniform base + lane*16
__device__ __forceinline__ void gload_lds16(const u16* g, u16* l) {
  __builtin_amdgcn_global_load_lds(
      (const __attribute__((address_space(1))) u32*)(uintptr_t)g,
      (__attribute__((address_space(3))) u32*)(u32)(uintptr_t)l,
      16, 0, 0);
}

// ---------- block-wide reduction of 4 values over 256 threads ----------
__device__ __forceinline__ void block_reduce4(float& a, float& b, float& c, float& d) {
  #pragma unroll
  for (int off = 32; off > 0; off >>= 1) {
    a += __shfl_down(a, off, 64);
    b += __shfl_down(b, off, 64);
    c += __shfl_down(c, off, 64);
    d += __shfl_down(d, off, 64);
  }
  __shared__ float red[4][4];
  int wid = threadIdx.x >> 6;
  int lane = threadIdx.x & 63;
  if (lane == 0) { red[0][wid] = a; red[1][wid] = b; red[2][wid] = c; red[3][wid] = d; }
  __syncthreads();
  a = red[0][0] + red[0][1] + red[0][2] + red[0][3];
  b = red[1][0] + red[1][1] + red[1][2] + red[1][3];
  c = red[2][0] + red[2][1] + red[2][2] + red[2][3];
  d = red[3][0] + red[3][1] + red[3][2] + red[3][3];
}

// ---------- K1 (fused): blocks 0..8191 = LayerNorm-1; 8192..8575 = weight prep.
__global__ __launch_bounds__(256) void prep_kernel(
    const float* __restrict__ x, const float* __restrict__ w, const float* __restrict__ bi,
    u16* __restrict__ xnr, u16* __restrict__ xni,
    const float* __restrict__ Wq, const float* __restrict__ Wk, const float* __restrict__ Wv,
    u16* __restrict__ wT) {
  const int tid = threadIdx.x;
  if (blockIdx.x < BT_) {
    // ---- ln1 body: LayerNorm over F per (b,t,plane); emit bf16 real/imag
    const int row = blockIdx.x;
    const int f = tid;
    float2 xv = reinterpret_cast<const float2*>(x)[row * F_ + f];
    float sr = xv.x, si = xv.y, sr2 = xv.x * xv.x, si2 = xv.y * xv.y;
    block_reduce4(sr, si, sr2, si2);
    const float inv = 1.0f / F_;
    float mr = sr * inv, mi = si * inv;
    float vr = sr2 * inv - mr * mr, vi = si2 * inv - mi * mi;
    float rr = rsqrtf(vr + EPS), ri = rsqrtf(vi + EPS);
    float ww = w[f], bb = bi[f];
    xnr[row * F_ + f] = f2bf((xv.x - mr) * rr * ww + bb);
    xni[row * F_ + f] = f2bf((xv.y - mi) * ri * ww + bb);
  } else {
    // ---- wprep body: transpose+convert W[z][f][h] (f32) -> wT[z][h][f] (bf16)
    const int wid = blockIdx.x - BT_;   // 0..383
    const int z = wid >> 4;             // 0..23
    const int r4 = wid & 15;
    const int ft = (r4 & 3) * 64;
    const int ht = (r4 >> 2) * 64;
    const int m = z >> 3, n = z & 7;
    const float* W = (m == 0 ? Wq : (m == 1 ? Wk : Wv)) + (size_t)n * F_ * H_;
    __shared__ __align__(16) u16 Ts[64][72];

    #pragma unroll
    for (int i = 0; i < 4; i++) {
      int id = tid + i * 256;
      int r = id >> 4, c4 = (id & 15) * 4;
      float4 p = *reinterpret_cast<const float4*>(&W[(size_t)(ft + r) * H_ + ht + c4]);
      Ts[r][c4 + 0] = f2bf(p.x); Ts[r][c4 + 1] = f2bf(p.y);
      Ts[r][c4 + 2] = f2bf(p.z); Ts[r][c4 + 3] = f2bf(p.w);
    }
    __syncthreads();
    u16* op = wT + (size_t)z * F_ * H_ + (size_t)ht * F_ + ft;
    #pragma unroll
    for (int i = 0; i < 2; i++) {
      int id = tid + i * 256;
      int hl = id & 63, g = id >> 6;
      u16 tmp[8];
      #pragma unroll
      for (int j = 0; j < 8; j++) tmp[j] = Ts[g * 8 + j][hl];
      *reinterpret_cast<uint4*>(op + (size_t)hl * F_ + g * 8) =
          *reinterpret_cast<const uint4*>(tmp);
    }
  }
}

// ---------- K2b: QKV projections — bf16 MFMA GEMM, 128x256 tile (full H) ----------
// R23 pipeline: counted-vmcnt double-buffer (attn-R14-proven template).
__global__ __launch_bounds__(256, 2) void qkv_kernel(
    const u16* __restrict__ xnr, const u16* __restrict__ xni, const u16* __restrict__ wT,
    const float* __restrict__ bq, const float* __restrict__ bk, const float* __restrict__ bv,
    u16* __restrict__ qo, u16* __restrict__ ko, u16* __restrict__ vTo) {
  const int z = blockIdx.y;
  const int m = z >> 3, n = z & 7;
  int sel; const float* bias; u16* out;
  if (m == 0)      { sel = (n >> 1) & 1;  bias = bq; out = qo + (size_t)n * BT_ * H_; }
  else if (m == 1) { sel = n & 1;         bias = bk; out = ko + (size_t)n * BT_ * H_; }
  else             { sel = __popc(n) & 1; bias = bv; out = nullptr; }
  const float osc = (m == 0) ? SCALE_L2E : 1.0f;   // q pre-scaled by 1/16*log2(e)
  const u16* A = sel ? xni : xnr;
  const u16* wp = wT + (size_t)z * F_ * H_;
  bias += n * H_;
  const int rowbase = blockIdx.x * 128;

  __shared__ __align__(16) u16 As[2][128 * 32];   // 16 KB, dbuf of BK=32 tiles
  __shared__ __align__(16) u16 Bs[2][256 * 32];   // 32 KB, dbuf of BK=32 tiles
  __shared__ __align__(16) u16 Epi[4][1536];      // q/k: [16][72]; v: [64][24]

  const int tid = threadIdx.x;
  const int wv = tid >> 6, lane = tid & 63;
  const int quad = lane >> 4, l16 = lane & 15;
  const int wrow = wv >> 1, wcol = wv & 1;        // wave: 64 rows x 128 cols

  f32x4 acc[4][8];
  #pragma unroll
  for (int i = 0; i < 4; i++)
    #pragma unroll
    for (int j = 0; j < 8; j++) acc[i][j] = (f32x4){0.f, 0.f, 0.f, 0.f};

  const int ar = tid >> 2;            // staging: row tid>>2, k-chunk (tid&3)*8
  const int ak = (tid & 3) * 8;

  // stage K-tile t (cols t*32..t*32+31) into buffer buf: 6 DMA instr-groups.
  auto stage = [&](int t, int buf) {
    const int kb = t * 32;
    gload_lds16(A + (size_t)(rowbase + ar) * F_ + kb + ak, &As[buf][tid * 8]);
    gload_lds16(A + (size_t)(rowbase + 64 + ar) * F_ + kb + ak,
                &As[buf][2048 + tid * 8]);
    #pragma unroll
    for (int c = 0; c < 4; c++)
      gload_lds16(wp + (size_t)(c * 64 + ar) * F_ + kb + ak,
                  &Bs[buf][c * 2048 + tid * 8]);
  };

  stage(0, 0);
  stage(1, 1);
  asm volatile("s_waitcnt vmcnt(6)" ::: "memory");   // tile 0 landed
  __builtin_amdgcn_s_barrier();
  __builtin_amdgcn_sched_barrier(0);

  #pragma unroll 1
  for (int t = 0; t < 8; t++) {
    const int c = t & 1;

    // ---- compute tile t from As[c]/Bs[c]: 12 ds_read_b128 + 32 mfma16
    bf16x8 a[4], b[8];
    #pragma unroll
    for (int mi = 0; mi < 4; mi++)
      a[mi] = *reinterpret_cast<const bf16x8*>(
          &As[c][(wrow * 64 + mi * 16 + l16) * 32 + quad * 8]);
    #pragma unroll
    for (int nj = 0; nj < 8; nj++)
      b[nj] = *reinterpret_cast<const bf16x8*>(
          &Bs[c][(wcol * 128 + nj * 16 + l16) * 32 + quad * 8]);
    __builtin_amdgcn_s_setprio(1);
    #pragma unroll
    for (int mi = 0; mi < 4; mi++)
      #pragma unroll
      for (int nj = 0; nj < 8; nj++)
        acc[mi][nj] = mfma16(a[mi], b[nj], acc[mi][nj]);
    __builtin_amdgcn_s_setprio(0);

    // ---- B1: all waves' reads of buf c retired -> c may be overwritten
    asm volatile("s_waitcnt lgkmcnt(0)" ::: "memory");
    __builtin_amdgcn_s_barrier();
    __builtin_amdgcn_sched_barrier(0);

    if (t < 6) stage(t + 2, c);

    // ---- B2: tile t+1 resident for all waves (counted vmcnt, no drain)
    if (t < 6) {
      asm volatile("s_waitcnt vmcnt(6)" ::: "memory");
    } else {
      asm volatile("s_waitcnt vmcnt(0)" ::: "memory");
    }
    __builtin_amdgcn_s_barrier();
    __builtin_amdgcn_sched_barrier(0);
  }

  float bias8[8];
  #pragma unroll
  for (int nj = 0; nj < 8; nj++)
    bias8[nj] = bias[wcol * 128 + nj * 16 + l16];

  if (m != 2) {   // q/k: row-major store, two 64-col passes
    #pragma unroll
    for (int pass = 0; pass < 2; pass++) {
      #pragma unroll
      for (int mi = 0; mi < 4; mi++) {
        #pragma unroll
        for (int nj4 = 0; nj4 < 4; nj4++) {
          int nj = pass * 4 + nj4;
          #pragma unroll
          for (int r = 0; r < 4; r++)
            Epi[wv][(quad * 4 + r) * 72 + nj4 * 16 + l16] =
                f2bf((acc[mi][nj][r] + bias8[nj]) * osc);
        }
        int row = rowbase + wrow * 64 + mi * 16 + l16;
        uint4 v0 = *reinterpret_cast<const uint4*>(&Epi[wv][l16 * 72 + quad * 16]);
        uint4 v1 = *reinterpret_cast<const uint4*>(&Epi[wv][l16 * 72 + quad * 16 + 8]);
        u16* op = out + (size_t)row * H_ + wcol * 128 + pass * 64 + quad * 16;
        *reinterpret_cast<uint4*>(op) = v0;
        *reinterpret_cast<uint4*>(op + 8) = v1;
      }
    }
  } else {        // v: transposed store into vT[n][h][bt], two 64-h passes
    #pragma unroll
    for (int pass = 0; pass < 2; pass++) {
      #pragma unroll
      for (int mi = 0; mi < 4; mi++) {
        #pragma unroll
        for (int nj4 = 0; nj4 < 4; nj4++) {
          int nj = pass * 4 + nj4;
          #pragma unroll
          for (int r = 0; r < 4; r++)
            Epi[wv][(nj4 * 16 + l16) * 24 + quad * 4 + r] =
                f2bf(acc[mi][nj][r] + bias8[nj]);
        }
        int hloc = lane;                  // 0..63
        uint4 w0 = *reinterpret_cast<const uint4*>(&Epi[wv][hloc * 24]);
        uint4 w1 = *reinterpret_cast<const uint4*>(&Epi[wv][hloc * 24 + 8]);
        u16* op = vTo + (size_t)n * H_ * BT_ +
                  (size_t)(wcol * 128 + pass * 64 + hloc) * BT_ +
                  rowbase + wrow * 64 + mi * 16;
        *reinterpret_cast<uint4*>(op) = w0;
        *reinterpret_cast<uint4*>(op + 8) = w1;
      }
    }
  }
}

// ---------- K3: MFMA flash attention ----------
// R25 == R23 attn exactly (session best: attn 102.3 us, total 165.8 us).
// R24's 2-qt-per-block grid REGRESSED (+8 us): serializing qt halved the
// concurrent blocks per nb -> K/V L2 temporal locality broken (FETCH 82->98,
// WRITE 32->49 MB). Reverted. Structure: counted vmcnt, split K/V prefetch,
// raw v_exp_f32 softmax (log2e pre-folded), full-depth XOR swizzles, 512
// one-qt blocks (nb = fid&63 -> XCD-local K/V sharing across 8 qt-blocks).
__global__ __launch_bounds__(512, 2) void attn_kernel(
    const u16* __restrict__ q, const u16* __restrict__ k, const u16* __restrict__ vT,
    u16* __restrict__ obuf) {
  const int fid = blockIdx.x;        // 0..511
  const int qt = fid >> 6;           // 0..7 : 128 query rows
  const int nb = fid & 63;           // n*8 + b ; XCD = nb & 7
  const int n = nb >> 3, b = nb & 7;
  const int tid = threadIdx.x;
  const int wv = tid >> 6, lane = tid & 63;
  const int hi = lane >> 5, l32 = lane & 31;
  const int qh = wv >> 1;            // q 32-row group (0..3)
  const int kh = wv & 1;             // QK: key-half (32 keys)
  const int hh = wv & 1;             // PV: h-half (128 h)

  const size_t base = (size_t)nb * T_ * H_;
  const u16* qp = q + base;          // pre-scaled by SCALE_L2E
  const u16* kp = k + base;
  const u16* vtp = vT + ((size_t)n * H_ * B_ + b) * T_;

  __shared__ __align__(16) u16 Ks[2][64][256];   // 64 KB, 5-bit XOR swizzle
  __shared__ __align__(16) u16 Vs[2][64][256];   // 64 KB, packed-4h + 3-bit XOR
  __shared__ __align__(16) u16 Ps[4][32][72];    // 18,432 B (cols 64..67: l-sums)

  const int qrow0 = qt * 128 + qh * 32;
  bf16x8 qf[16];
  #pragma unroll
  for (int kc = 0; kc < 16; kc++)
    qf[kc] = *reinterpret_cast<const bf16x8*>(
        qp + (size_t)(qrow0 + l32) * H_ + kc * 16 + hi * 8);

  f32x16 o[4];
  #pragma unroll
  for (int ot = 0; ot < 4; ot++)
    #pragma unroll
    for (int r = 0; r < 16; r++) o[ot][r] = 0.f;
  float lper[16];
  #pragma unroll
  for (int r = 0; r < 16; r++) lper[r] = 0.f;

  // K staging: 32 DMA instrs (4/wave), each fills 2 rows (512B each).
  auto stage_k = [&](int ktN, int buf) {
    #pragma unroll
    for (int i = 0; i < 4; i++) {
      int idx = wv * 4 + i;
      int row = 2 * idx + hi;
      const u16* src = kp + (size_t)(ktN * 64 + row) * H_ +
                       ((l32 ^ (row & 31)) * 8);
      gload_lds16(src, &Ks[buf][2 * idx][0]);
    }
  };
  // V staging: 32 DMA instrs (4/wave), each fills 2 physical rows.
  auto stage_v = [&](int ktN, int buf) {
    #pragma unroll
    for (int i = 0; i < 4; i++) {
      int idx = wv * 4 + i;
      int p = 2 * idx + hi;
      int u = l32 ^ (p & 7);
      const u16* src = vtp + (size_t)(p * 4 + (u >> 3)) * BT_ +
                       ktN * 64 + (u & 7) * 8;
      gload_lds16(src, &Vs[buf][2 * idx][0]);
    }
  };

  // Prologue: stage tiles 0 and 1; wait only tile 0 (own 8 newest = tile 1).
  stage_k(0, 0); stage_v(0, 0);
  stage_k(1, 1); stage_v(1, 1);
  asm volatile("s_waitcnt vmcnt(8)" ::: "memory");
  __builtin_amdgcn_s_barrier();
  __builtin_amdgcn_sched_barrier(0);

  const int krow = kh * 32 + l32;

  #pragma unroll 1
  for (int kt = 0; kt < 16; kt++) {
    const int c = kt & 1;

    // ---- QK phase: reads Ks[c]
    f32x16 sa, sb;
    #pragma unroll
    for (int r = 0; r < 16; r++) { sa[r] = 0.f; sb[r] = 0.f; }
    __builtin_amdgcn_s_setprio(1);
    #pragma unroll
    for (int kc = 0; kc < 16; kc += 2) {
      bf16x8 kfa = *reinterpret_cast<const bf16x8*>(
          &Ks[c][krow][(((kc * 2 + hi) ^ l32) * 8)]);
      bf16x8 kfb = *reinterpret_cast<const bf16x8*>(
          &Ks[c][krow][(((kc * 2 + 2 + hi) ^ l32) * 8)]);
      sa = mfma32(qf[kc], kfa, sa);
      sb = mfma32(qf[kc + 1], kfb, sb);
    }
    __builtin_amdgcn_s_setprio(0);

    #pragma unroll
    for (int r = 0; r < 16; r++) {
      float p = __builtin_amdgcn_exp2f(sa[r] + sb[r]);  // log2e pre-folded
      lper[r] += p;
      Ps[qh][(r & 3) + 8 * (r >> 2) + 4 * hi][kh * 32 + l32] = f2bf(p);
    }

    // ---- B1: Ps writes visible; Ks[c] readers (all waves) retired.
    asm volatile("s_waitcnt lgkmcnt(0)" ::: "memory");
    __builtin_amdgcn_s_barrier();
    __builtin_amdgcn_sched_barrier(0);

    if (kt < 14) stage_k(kt + 2, c);

    // ---- PV phase: reads Ps + Vs[c]
    bf16x8 pa[4];
    #pragma unroll
    for (int kc2 = 0; kc2 < 4; kc2++)
      pa[kc2] = *reinterpret_cast<const bf16x8*>(
          &Ps[qh][l32][kc2 * 16 + hi * 8]);
    __builtin_amdgcn_s_setprio(1);
    #pragma unroll
    for (int ot = 0; ot < 4; ot++) {
      const int p = hh * 32 + ot * 8 + (l32 >> 2);
      #pragma unroll
      for (int kc2 = 0; kc2 < 4; kc2++) {
        int s = ((l32 & 3) * 8 + kc2 * 2 + hi) ^ (l32 >> 2);
        bf16x8 vf = *reinterpret_cast<const bf16x8*>(&Vs[c][p][s * 8]);
        o[ot] = mfma32(pa[kc2], vf, o[ot]);
      }
    }
    __builtin_amdgcn_s_setprio(0);

    // ---- B2: own K/V(kt+1) landed; Vs[c]/Ps readers retired.
    if (kt < 14) {
      asm volatile("s_waitcnt vmcnt(4)" ::: "memory");
    } else {
      asm volatile("s_waitcnt vmcnt(0)" ::: "memory");
    }
    __builtin_amdgcn_s_barrier();
    __builtin_amdgcn_sched_barrier(0);

    if (kt < 14) stage_v(kt + 2, c);
  }

  #pragma unroll
  for (int r = 0; r < 16; r++) {
    #pragma unroll
    for (int off = 1; off < 32; off <<= 1)
      lper[r] += __shfl_xor(lper[r], off, 64);
  }
  if (l32 == 0) {
    #pragma unroll
    for (int r = 0; r < 16; r++) {
      int row = (r & 3) + 8 * (r >> 2) + 4 * hi;
      *reinterpret_cast<float*>(&Ps[qh][row][64 + 2 * kh]) = lper[r];
    }
  }
  __syncthreads();

  float invl[16];
  #pragma unroll
  for (int r = 0; r < 16; r++) {
    int row = (r & 3) + 8 * (r >> 2) + 4 * hi;
    float l0 = *reinterpret_cast<const float*>(&Ps[qh][row][64]);
    float l1 = *reinterpret_cast<const float*>(&Ps[qh][row][66]);
    invl[r] = 1.0f / (l0 + l1);
  }

  u16* Ew = reinterpret_cast<u16*>(&Ks[0][0][0]) + wv * 1280;   // 8x1280 u16
  const int grow = b * 1024 + qrow0 + l32;
  #pragma unroll
  for (int ot = 0; ot < 4; ot++) {
    #pragma unroll
    for (int r = 0; r < 16; r++) {
      int row = (r & 3) + 8 * (r >> 2) + 4 * hi;
      Ew[row * 40 + l32] = f2bf(o[ot][r] * invl[r]);
    }
    int ht = hh * 4 + ot;
    uint4 v0 = *reinterpret_cast<const uint4*>(&Ew[l32 * 40 + hi * 16]);
    uint4 v1 = *reinterpret_cast<const uint4*>(&Ew[l32 * 40 + hi * 16 + 8]);
    u16* op = obuf + (((size_t)n * 8 + ht) * BT_ + grow) * 32 + hi * 16;
    *reinterpret_cast<uint4*>(op) = v0;
    *reinterpret_cast<uint4*>(op + 8) = v1;
  }
}

// ---------- K4: combine 8 branches (signed) + LayerNorm over H ----------
__global__ __launch_bounds__(256) void combine_ln2_kernel(
    const u16* __restrict__ obuf, const float* __restrict__ w,
    const float* __restrict__ bi, float* __restrict__ out) {
  const int row = blockIdx.x;
  const int h = threadIdx.x;
  float o[8];
  #pragma unroll
  for (int nn = 0; nn < 8; nn++)
    o[nn] = bf1(obuf[(((size_t)nn * 8 + (h >> 5)) * BT_ + row) * 32 + (h & 31)]);
  float re = o[0] - o[1] - o[2] - o[3];
  float im = o[4] + o[5] + o[6] - o[7];
  float sr = re, si = im, sr2 = re * re, si2 = im * im;
  block_reduce4(sr, si, sr2, si2);
  const float inv = 1.0f / H_;
  float mr = sr * inv, mi = si * inv;
  float vr = sr2 * inv - mr * mr, vi = si2 * inv - mi * mi;
  float rr = rsqrtf(vr + EPS), ri = rsqrtf(vi + EPS);
  float ww = w[h], bb = bi[h];
  float2 res;
  res.x = (re - mr) * rr * ww + bb;
  res.y = (im - mi) * ri * ww + bb;
  reinterpret_cast<float2*>(out)[(size_t)row * H_ + h] = res;
}

extern "C" void kernel_launch(void* const* d_in, const int* in_sizes, int n_in,
                              void* d_out, int out_size, void* d_ws, size_t ws_size,
                              hipStream_t stream) {
  const float* x    = (const float*)d_in[0];
  const float* Wq   = (const float*)d_in[1];
  const float* bq   = (const float*)d_in[2];
  const float* Wk   = (const float*)d_in[3];
  const float* bk   = (const float*)d_in[4];
  const float* Wv   = (const float*)d_in[5];
  const float* bv   = (const float*)d_in[6];
  const float* ln1w = (const float*)d_in[7];
  const float* ln1b = (const float*)d_in[8];
  const float* ln2w = (const float*)d_in[9];
  const float* ln2b = (const float*)d_in[10];

  // Workspace (128 MB), lifetime-aliased:
  //  [0,8)  xn  (dead after qkv)  |  [0,32)  obuf (written by attn, after qkv)
  //  [8,11) wT  (dead after qkv)
  //  [32,64) vT ; [64,96) q ; [96,128) k
  char* ws = (char*)d_ws;
  u16* xnr  = (u16*)(ws);
  u16* xni  = (u16*)(ws + (4ull  << 20));
  u16* wTb  = (u16*)(ws + (8ull  << 20));
  u16* obuf = (u16*)(ws);
  u16* vT   = (u16*)(ws + (32ull << 20));
  u16* qbuf = (u16*)(ws + (64ull << 20));
  u16* kbuf = (u16*)(ws + (96ull << 20));

  prep_kernel<<<BT_ + 384, 256, 0, stream>>>(x, ln1w, ln1b, xnr, xni,
                                             Wq, Wk, Wv, wTb);
  qkv_kernel<<<dim3(64, 24), 256, 0, stream>>>(xnr, xni, wTb, bq, bk, bv,
                                               qbuf, kbuf, vT);
  attn_kernel<<<dim3(512), 512, 0, stream>>>(qbuf, kbuf, vT, obuf);
  combine_ln2_kernel<<<BT_, 256, 0, stream>>>(obuf, ln2w, ln2b, (float*)d_out);
}